// Round 9
// baseline (263.836 us; speedup 1.0000x reference)
//
#include <hip/hip_runtime.h>
#include <hip/hip_bf16.h>
#include <stdint.h>

// Problem constants (fixed by the reference)
#define NS   8192
#define XD   512
#define HD   2048
#define YD   512

typedef unsigned short u16;
using bf16x8 = __attribute__((ext_vector_type(8))) short;
using f32x4  = __attribute__((ext_vector_type(4))) float;

__device__ __forceinline__ float bf2f(u16 u) {
  union { uint32_t i; float f; } v; v.i = ((uint32_t)u) << 16; return v.f;
}
__device__ __forceinline__ u16 f2b(float f) {
  __hip_bfloat16 hb = __float2bfloat16(f);
  return *(const u16*)&hb;
}
// dtype-adaptive element load: f32 flag ? read float : read bf16
__device__ __forceinline__ float ld_in(const void* p, int f32, size_t i) {
  return f32 ? ((const float*)p)[i] : bf2f(((const u16*)p)[i]);
}
#define GLDS(gp, lp) __builtin_amdgcn_global_load_lds( \
    (__attribute__((address_space(1))) void*)(gp),     \
    (__attribute__((address_space(3))) void*)(lp), 16, 0, 0)

// ---------------- per-block dtype self-detection ----------------------------
__device__ __forceinline__ int probe_f32(const void* p, int n_u16, int* sflag) {
  if (threadIdx.x == 0) *sflag = 0;
  __syncthreads();
  const u16* q = (const u16*)p;
  int wild = 0;
  for (int i = threadIdx.x; i < n_u16; i += blockDim.x) {
    float v = bf2f(q[i]);
    if (!(fabsf(v) <= 1000.0f)) wild = 1;   // catches huge AND NaN
  }
  if (wild) *sflag = 1;
  __syncthreads();
  int r = *sflag;
  __syncthreads();                          // safe for back-to-back reuse
  return r;
}

// ---------------- fused prep: x->bf16, biases, 4 transposes, ystats ---------
// grid: [0,2048) x-convert | 2048 biases | [2049,3073) transposes |
//       [3073,3137) y column stats
__global__ __launch_bounds__(256) void prep_all(
    const void* __restrict__ x,
    const void* w1m, const void* b1m, const void* w2m, const void* b2m,
    const void* w1l, const void* b1l, const void* w2l, const void* b2l,
    const void* __restrict__ y,
    u16* __restrict__ xb, float* __restrict__ biasv,
    u16* __restrict__ W1t, u16* __restrict__ W2tm, u16* __restrict__ W2tl,
    float* __restrict__ Sy, float* __restrict__ Sy2) {
  __shared__ u16 tile[64 * 72];              // transpose staging (9216 B)
  __shared__ int sflag;
  const int b = blockIdx.x;
  const int tid = threadIdx.x;

  if (b < 2048) {                            // ---- x conversion (f32 only)
    if (!probe_f32(x, 1024, &sflag)) return; // bf16 -> gemm1 reads x directly
    const size_t base = (size_t)b * 2048 + (size_t)tid * 8;
    alignas(16) u16 o[8];
    const float4* s = (const float4*)((const float*)x + base);
    float4 v0 = s[0], v1 = s[1];
    o[0]=f2b(v0.x); o[1]=f2b(v0.y); o[2]=f2b(v0.z); o[3]=f2b(v0.w);
    o[4]=f2b(v1.x); o[5]=f2b(v1.y); o[6]=f2b(v1.z); o[7]=f2b(v1.w);
    *(uint4*)(xb + base) = *(const uint4*)o;
  } else if (b == 2048) {                    // ---- biases -> f32
    const int f3 = probe_f32(b1m, 1024, &sflag);
    const int f5 = probe_f32(b2m, 512, &sflag);
    const int f7 = probe_f32(b1l, 1024, &sflag);
    const int f9 = probe_f32(b2l, 512, &sflag);
    for (int i = tid; i < 5120; i += 256) {
      float v;
      if (i < 2048)      v = ld_in(b1m, f3, i);
      else if (i < 4096) v = ld_in(b1l, f7, i - 2048);
      else if (i < 4608) v = ld_in(b2m, f5, i - 4096);
      else               v = ld_in(b2l, f9, i - 4608);
      biasv[i] = v;
    }
  } else if (b < 3073) {                     // ---- 64x64-tile transposes
    const int id = b - 2049, which = id >> 8, t = id & 255;
    const void* in; u16* out; int R, C;
    if (which == 0)      { in = w1m; out = W1t;                   R = XD; C = HD; }
    else if (which == 1) { in = w2m; out = W2tm;                  R = HD; C = YD; }
    else if (which == 2) { in = w1l; out = W1t + (size_t)HD * XD; R = XD; C = HD; }
    else                 { in = w2l; out = W2tl;                  R = HD; C = YD; }
    const int f = probe_f32(in, 1024, &sflag);
    const int nbx = C >> 6;
    const int c0 = (t % nbx) * 64, r0 = (t / nbx) * 64;
    const int r = tid >> 2, cc = (tid & 3) * 16;
    if (f) {
      const float4* s = (const float4*)((const float*)in + (size_t)(r0 + r) * C + c0 + cc);
#pragma unroll
      for (int k = 0; k < 4; ++k) {
        float4 v = s[k];
        tile[r * 72 + cc + k * 4 + 0] = f2b(v.x);
        tile[r * 72 + cc + k * 4 + 1] = f2b(v.y);
        tile[r * 72 + cc + k * 4 + 2] = f2b(v.z);
        tile[r * 72 + cc + k * 4 + 3] = f2b(v.w);
      }
    } else {
      const uint4* s = (const uint4*)((const u16*)in + (size_t)(r0 + r) * C + c0 + cc);
      *(uint4*)&tile[r * 72 + cc]     = s[0];
      *(uint4*)&tile[r * 72 + cc + 8] = s[1];
    }
    __syncthreads();
    const int i = tid >> 2, jc = (tid & 3) * 16;
    alignas(16) u16 o[16];
#pragma unroll
    for (int j = 0; j < 16; ++j) o[j] = tile[(jc + j) * 72 + i];
    uint4* dq = (uint4*)&out[(size_t)(c0 + i) * R + r0 + jc];
    dq[0] = ((const uint4*)o)[0];
    dq[1] = ((const uint4*)o)[1];
  } else {                                   // ---- y column stats (64 blocks)
    const int id2 = b - 3073;
    const int yf = probe_f32(y, 1024, &sflag);
    const int half = tid >> 7;               // 0/1
    const int c0 = (tid & 127) * 4;
    const int r0 = id2 * 128 + half * 64;
    float s0 = 0.f, s1 = 0.f, s2 = 0.f, s3 = 0.f;
    float q0 = 0.f, q1 = 0.f, q2 = 0.f, q3 = 0.f;
    for (int r = r0; r < r0 + 64; r += 4) {
#pragma unroll
      for (int rr = 0; rr < 4; ++rr) {
        float v0, v1, v2, v3;
        if (yf) {
          const float4 t4 = *(const float4*)((const float*)y + (size_t)(r + rr) * YD + c0);
          v0 = t4.x; v1 = t4.y; v2 = t4.z; v3 = t4.w;
        } else {
          const uint2 t2 = *(const uint2*)((const u16*)y + (size_t)(r + rr) * YD + c0);
          v0 = bf2f((u16)(t2.x & 0xffff)); v1 = bf2f((u16)(t2.x >> 16));
          v2 = bf2f((u16)(t2.y & 0xffff)); v3 = bf2f((u16)(t2.y >> 16));
        }
        s0 += v0; q0 += v0 * v0;  s1 += v1; q1 += v1 * v1;
        s2 += v2; q2 += v2 * v2;  s3 += v3; q3 += v3 * v3;
      }
    }
    atomicAdd(&Sy[c0],     s0);  atomicAdd(&Sy2[c0],     q0);
    atomicAdd(&Sy[c0 + 1], s1);  atomicAdd(&Sy2[c0 + 1], q1);
    atomicAdd(&Sy[c0 + 2], s2);  atomicAdd(&Sy2[c0 + 2], q2);
    atomicAdd(&Sy[c0 + 3], s3);  atomicAdd(&Sy2[c0 + 3], q3);
  }
}

// ---------------- shared sync/pipeline macros -------------------------------
#define SYNC_PRE do { \
  __builtin_amdgcn_sched_barrier(0); \
  __builtin_amdgcn_s_barrier(); \
  asm volatile("s_waitcnt lgkmcnt(0)" ::: "memory"); \
  __builtin_amdgcn_sched_barrier(0); \
  __builtin_amdgcn_s_setprio(1); } while (0)
#define SYNC_POST do { \
  __builtin_amdgcn_s_setprio(0); \
  __builtin_amdgcn_sched_barrier(0); \
  __builtin_amdgcn_s_barrier(); \
  __builtin_amdgcn_sched_barrier(0); } while (0)
#define VMCNT(N) asm volatile("s_waitcnt vmcnt(" #N ")" ::: "memory")
#define LGKM(N) asm volatile("s_waitcnt lgkmcnt(" #N ")" ::: "memory")
#define SCB __builtin_amdgcn_sched_barrier(0)

// ---------------- GEMM1: 256x256 tile, 8-phase counted-vmcnt pipeline -------
// (verified round-0; unchanged)
#define RD_A(MH, BUF) do { \
  const u16* ab_ = &lds[((BUF)*2 + wm) * 8192]; \
  _Pragma("unroll") for (int q_ = 0; q_ < 4; ++q_) \
    _Pragma("unroll") for (int ks_ = 0; ks_ < 2; ++ks_) \
      af[q_][ks_] = *(const bf16x8*)&ab_[((MH)*64 + q_*16 + c16)*64 + (((ks_*4+quad) ^ cswz) << 3)]; \
} while (0)

#define RD_B(NH, BUF) do { \
  const u16* bb_ = &lds[32768 + ((BUF)*2 + (wn>>1)) * 8192]; \
  _Pragma("unroll") for (int p_ = 0; p_ < 2; ++p_) \
    _Pragma("unroll") for (int ks_ = 0; ks_ < 2; ++ks_) \
      bf[(NH)*2+p_][ks_] = *(const bf16x8*)&bb_[((wn&1)*64 + ((NH)*2+p_)*16 + c16)*64 + (((ks_*4+quad) ^ cswz) << 3)]; \
} while (0)

#define MM(MH, NH) do { \
  _Pragma("unroll") for (int ks_ = 0; ks_ < 2; ++ks_) \
    _Pragma("unroll") for (int q_ = 0; q_ < 4; ++q_) \
      _Pragma("unroll") for (int p_ = 0; p_ < 2; ++p_) \
        acc[(MH)*4+q_][(NH)*2+p_] = __builtin_amdgcn_mfma_f32_16x16x32_bf16( \
            af[q_][ks_], bf[(NH)*2+p_][ks_], acc[(MH)*4+q_][(NH)*2+p_], 0, 0, 0); \
} while (0)

#define ST_A(KT, HALF) do { if ((KT) < 8) { \
  u16* lb_ = &lds[(((KT)&1)*2 + (HALF))*8192 + (wid << 9)]; \
  const u16* sp_ = Aptr + (size_t)(bm0 + (HALF)*128 + (wid<<3) + srow)*512 + ((KT)<<6) + scg; \
  GLDS(sp_, lb_); GLDS(sp_ + (size_t)64*512, lb_ + 4096); } } while (0)

#define ST_B(KT, HALF) do { if ((KT) < 8) { \
  u16* lb_ = &lds[32768 + (((KT)&1)*2 + (HALF))*8192 + (wid << 9)]; \
  const u16* sp_ = W1t + (size_t)(bn0 + (HALF)*128 + (wid<<3) + srow)*512 + ((KT)<<6) + scg; \
  GLDS(sp_, lb_); GLDS(sp_ + (size_t)64*512, lb_ + 4096); } } while (0)

__global__ __launch_bounds__(512, 2) void gemm1_kernel(
    const void* __restrict__ xraw, const u16* __restrict__ xb,
    const u16* __restrict__ W1t,    // [4096, 512]
    const float* __restrict__ bias, // [4096]
    u16* __restrict__ h_mu, u16* __restrict__ h_lv) {
  __shared__ alignas(16) u16 lds[65536];     // 128 KB
  __shared__ int sflag;
  const int tid = threadIdx.x;

  const u16* Aptr = probe_f32(xraw, 1024, &sflag) ? xb : (const u16*)xraw;

  const int wid = tid >> 6, lane = tid & 63;
  const int wm = wid >> 2, wn = wid & 3;
  const int quad = lane >> 4, c16 = lane & 15, cswz = c16 & 7;
  const int srow = lane >> 3;
  const int scg  = ((lane & 7) ^ srow) << 3;

  const int id = blockIdx.x;
  const int xcd = id & 7, slot = id >> 3;    // 512 blocks, 64 slots/XCD
  const int bm0 = (xcd * 4 + (slot & 3)) * 256;
  const int bn0 = (slot >> 2) * 256;

  f32x4 acc[8][4] = {};
  bf16x8 af[4][2], bf[4][2];

  ST_B(0, 0); ST_B(0, 1); ST_A(0, 0); ST_A(0, 1);
  ST_B(1, 0); ST_B(1, 1);
  VMCNT(4);
  __builtin_amdgcn_s_barrier();
  __builtin_amdgcn_sched_barrier(0);

#pragma unroll
  for (int i = 0; i < 4; ++i) {
    const int ka = 2 * i, kb = ka + 1;
    const bool last = (i == 3);
    RD_A(0, 0); RD_B(0, 0); ST_A(kb, 0);
    SYNC_PRE; MM(0, 0); SYNC_POST;
    RD_B(1, 0); ST_A(kb, 1);
    SYNC_PRE; MM(0, 1); SYNC_POST;
    RD_A(1, 0); ST_B(ka + 2, 0);
    SYNC_PRE; MM(1, 0); SYNC_POST;
    ST_B(ka + 2, 1);
    SYNC_PRE; MM(1, 1);
    if (!last) { VMCNT(4); } else { VMCNT(0); }
    SYNC_POST;
    RD_A(0, 1); RD_B(0, 1); ST_A(ka + 2, 0);
    SYNC_PRE; MM(0, 0); SYNC_POST;
    RD_B(1, 1); ST_A(ka + 2, 1);
    SYNC_PRE; MM(0, 1); SYNC_POST;
    RD_A(1, 1); ST_B(kb + 2, 0);
    SYNC_PRE; MM(1, 0); SYNC_POST;
    ST_B(kb + 2, 1);
    SYNC_PRE; MM(1, 1);
    if (!last) { VMCNT(4); }
    SYNC_POST;
  }

  u16* myl = &lds[wid * 8192];
  const bool is_lv = bn0 >= HD;
  u16* dst = is_lv ? h_lv : h_mu;
  const int wncol = wn << 6;
  const int gc0 = (bn0 - (is_lv ? HD : 0)) + wncol;
  const int grow0 = bm0 + (wm << 7);
#pragma unroll
  for (int ni = 0; ni < 4; ++ni) {
    const float bv = bias[bn0 + wncol + ni * 16 + c16];
#pragma unroll
    for (int mi = 0; mi < 8; ++mi)
#pragma unroll
      for (int r = 0; r < 4; ++r) {
        const int row = mi * 16 + (quad << 2) + r;
        const int col = ni * 16 + c16;
        myl[row * 64 + ((((col >> 3) ^ (row & 7)) << 3) | (col & 7))] =
            f2b(fmaxf(acc[mi][ni][r] + bv, 0.f));
      }
  }
#pragma unroll
  for (int it = 0; it < 16; ++it) {
    const int row = (it << 3) + (lane >> 3);
    const int ch = lane & 7;
    const uint4 v = *(const uint4*)&myl[row * 64 + ((ch ^ (row & 7)) << 3)];
    *(uint4*)&dst[(size_t)(grow0 + row) * HD + gc0 + (ch << 3)] = v;
  }
}

#undef RD_A
#undef RD_B
#undef MM
#undef ST_A
#undef ST_B

// ---------------- GEMM2 v9: v7 dataflow, bump-pointer addrs, GLDS offset 0 --
// Round-8 failed correctness; the only first-use mechanism was the GLDS
// builtin's offset arg (semantics unprobed on gfx950) -> eliminated. v9 keeps
// v8's zero-temp addressing via DEDICATED staging pointers pre-advanced 2
// tiles in the prologue; all GLDS use offset 0 (validated rounds 0-2); A-side
// asm immediate offsets validated in v7 (offset:64). Schedule == v7 (passed):
//   PH(t): RD 8 ds from buf[t%3] | STB2 tile t+2 (stage ptrs) -> buf[(t+2)%3]
//          VMCNT(8) retires G(t+1)+aLo(t); LGKM(4) -> MM lo; LDA lo(t+1)
//          VMCNT(8) retires aHi(t);       LGKM(0) -> MM hi; LDA hi(t+1)
//          barrier; bump all ptrs +128 B.
// Steady in-flight entering phase: [G(t+1)4, aLo(t)4, aHi(t)4] = 12.
// WAR ring proof as v7 (reads retire via LGKM(0) before barrier; writer
// issues after passing it). Prologue VMCNT(12); tail 4 -> 4 -> 0.
// Ledger: frags 64 + aA 8 + stage ptrs 8 + misc ~15 = ~95 arch; acc -> AGPR.
#define LDA4LO_P do { \
  asm volatile("global_load_dwordx4 %0, %1, off" : "=v"(afLo[0]) : "v"(aA[0])); \
  asm volatile("global_load_dwordx4 %0, %1, off" : "=v"(afLo[1]) : "v"(aA[1])); \
  asm volatile("global_load_dwordx4 %0, %1, off" : "=v"(afLo[2]) : "v"(aA[2])); \
  asm volatile("global_load_dwordx4 %0, %1, off" : "=v"(afLo[3]) : "v"(aA[3])); \
} while (0)
#define LDA4HI_P do { \
  asm volatile("global_load_dwordx4 %0, %1, off offset:64" : "=v"(afHi[0]) : "v"(aA[0])); \
  asm volatile("global_load_dwordx4 %0, %1, off offset:64" : "=v"(afHi[1]) : "v"(aA[1])); \
  asm volatile("global_load_dwordx4 %0, %1, off offset:64" : "=v"(afHi[2]) : "v"(aA[2])); \
  asm volatile("global_load_dwordx4 %0, %1, off offset:64" : "=v"(afHi[3]) : "v"(aA[3])); \
} while (0)
#define LDA4LO_N do { \
  asm volatile("global_load_dwordx4 %0, %1, off offset:128" : "=v"(afLo[0]) : "v"(aA[0])); \
  asm volatile("global_load_dwordx4 %0, %1, off offset:128" : "=v"(afLo[1]) : "v"(aA[1])); \
  asm volatile("global_load_dwordx4 %0, %1, off offset:128" : "=v"(afLo[2]) : "v"(aA[2])); \
  asm volatile("global_load_dwordx4 %0, %1, off offset:128" : "=v"(afLo[3]) : "v"(aA[3])); \
} while (0)
#define LDA4HI_N do { \
  asm volatile("global_load_dwordx4 %0, %1, off offset:192" : "=v"(afHi[0]) : "v"(aA[0])); \
  asm volatile("global_load_dwordx4 %0, %1, off offset:192" : "=v"(afHi[1]) : "v"(aA[1])); \
  asm volatile("global_load_dwordx4 %0, %1, off offset:192" : "=v"(afHi[2]) : "v"(aA[2])); \
  asm volatile("global_load_dwordx4 %0, %1, off offset:192" : "=v"(afHi[3]) : "v"(aA[3])); \
} while (0)

#define RD4(BF, BUFI, KS) do { \
  _Pragma("unroll") for (int ni_ = 0; ni_ < 4; ++ni_) \
    BF[ni_] = *(const bf16x8*)&lds[(BUFI)*16384 + rbase + \
        (wn*64 + ni_*16 + c16)*64 + ((((KS)*4+quad) ^ cswz) << 3)]; \
} while (0)

#define MM16(AF, BF) do { \
  _Pragma("unroll") for (int mi_ = 0; mi_ < 4; ++mi_) \
    _Pragma("unroll") for (int ni_ = 0; ni_ < 4; ++ni_) \
      acc[mi_][ni_] = __builtin_amdgcn_mfma_f32_16x16x32_bf16( \
          AF[mi_], BF[ni_], acc[mi_][ni_], 0, 0, 0); \
} while (0)

// Stage (offset 0) from the dedicated staging pointers into ring buffer BI.
#define STB2(BI) do { \
  u16* lbm_ = lds + (BI)*16384 + (wid << 9); \
  GLDS(sMp, lbm_); GLDS(sMp2, lbm_ + 4096); \
  u16* lbl_ = lbm_ + 8192; \
  GLDS(sLp, lbl_); GLDS(sLp2, lbl_ + 4096); \
} while (0)

#define BUMPS do { sMp += 64; sLp += 64; sMp2 += 64; sLp2 += 64; } while (0)
#define BUMP  do { \
  aA[0] += 128u; aA[1] += 128u; aA[2] += 128u; aA[3] += 128u; \
  BUMPS; \
} while (0)

#define PH9(BR, BS) do { \
  SCB; RD4(bfLo, BR, 0); RD4(bfHi, BR, 1); SCB; \
  STB2(BS); SCB; \
  VMCNT(8); LGKM(4); SCB; \
  __builtin_amdgcn_s_setprio(1); MM16(afLo, bfLo); __builtin_amdgcn_s_setprio(0); SCB; \
  LDA4LO_N; SCB; \
  VMCNT(8); LGKM(0); SCB; \
  __builtin_amdgcn_s_setprio(1); MM16(afHi, bfHi); __builtin_amdgcn_s_setprio(0); SCB; \
  LDA4HI_N; SCB; \
  __builtin_amdgcn_s_barrier(); SCB; \
  BUMP; SCB; \
} while (0)

__global__ __launch_bounds__(512, 2) void gemm2_dual(
    const u16* __restrict__ hm, const u16* __restrict__ hl,
    const u16* __restrict__ W2m, const u16* __restrict__ W2l,  // [YD, HD]
    const float* __restrict__ b2m, const float* __restrict__ b2l,
    const void* __restrict__ y,
    const float* __restrict__ Sy, const float* __restrict__ Sy2,
    double* __restrict__ gacc, unsigned* __restrict__ counter,
    float* __restrict__ out) {
  __shared__ alignas(16) u16 lds[49152];     // 96 KB: 3 bufs x 32 KB
  __shared__ double bs[8];
  __shared__ int sflag;

  const int yf = probe_f32(y, 1024, &sflag);

  const int tid = threadIdx.x, wid = tid >> 6, lane = tid & 63;
  const int wh = wid >> 2;                   // 0 = mu, 1 = lv
  const int wm = (wid >> 1) & 1, wn = wid & 1;  // 2M x 2N within head
  const int quad = lane >> 4, c16 = lane & 15, cswz = c16 & 7;
  const int srow = lane >> 3;
  const int scg  = ((lane & 7) ^ srow) << 3;
  const int rbase = wh * 8192;               // Bm@0 / Bl@8192 u16 within buf

  // 256 blocks = 64 m-tiles x 4 n-tiles; N-fastest within XCD.
  const int id = blockIdx.x;
  const int xcd = id & 7, slot = id >> 3;    // 32 slots/XCD
  const int bm0 = (xcd * 8 + (slot >> 2)) * 128;
  const int bn0 = (slot & 3) * 128;

  // B staging pointers (bumped 64 u16 = 128 B per stage/phase).
  const u16* sMp  = W2m + (size_t)(bn0 + (wid << 3) + srow) * HD + scg;
  const u16* sLp  = W2l + (size_t)(bn0 + (wid << 3) + srow) * HD + scg;
  const u16* sMp2 = sMp + (size_t)64 * HD;
  const u16* sLp2 = sLp + (size_t)64 * HD;

  // A fragment base byte-addresses (bumped 128 B per phase).
  const u16* hx = wh ? hl : hm;
  uint64_t aA[4];
#pragma unroll
  for (int mi = 0; mi < 4; ++mi)
    aA[mi] = (uint64_t)(uintptr_t)(
        hx + (size_t)(bm0 + wm * 64 + mi * 16 + c16) * HD + quad * 8);

  f32x4 acc[4][4] = {};
  bf16x8 afLo[4], afHi[4], bfLo[4], bfHi[4];

  // Prologue: stage tile 0 -> buf0, bump, tile 1 -> buf1, bump (ptrs at
  // tile 2); load A(0) lo+hi; retire G(0); barrier.
  STB2(0); BUMPS;
  STB2(1); BUMPS;
  SCB;
  LDA4LO_P; LDA4HI_P;
  SCB;
  VMCNT(12);                                 // retires G(0); 12 remain
  __builtin_amdgcn_s_barrier();
  SCB;

  // 30 steady phases (ring period 3), then 2 peeled tail phases.
#pragma unroll 1
  for (int i = 0; i < 10; ++i) {
    PH9(0, 2);
    PH9(1, 0);
    PH9(2, 1);
  }
  // Phase 30 (buf0): no stage; in-flight [G(31)4, aLo(30)4, aHi(30)4] = 12.
  SCB; RD4(bfLo, 0, 0); RD4(bfHi, 0, 1); SCB;
  VMCNT(4); LGKM(4); SCB;                    // retires G(31)+aLo(30)
  __builtin_amdgcn_s_setprio(1); MM16(afLo, bfLo); __builtin_amdgcn_s_setprio(0); SCB;
  LDA4LO_N; SCB;                             // A(31) lo  (base at tile 30)
  VMCNT(4); LGKM(0); SCB;                    // retires aHi(30)
  __builtin_amdgcn_s_setprio(1); MM16(afHi, bfHi); __builtin_amdgcn_s_setprio(0); SCB;
  LDA4HI_N; SCB;                             // A(31) hi
  __builtin_amdgcn_s_barrier(); SCB;
  // Phase 31 (buf1): drain.
  RD4(bfLo, 1, 0); RD4(bfHi, 1, 1); SCB;
  VMCNT(4); LGKM(4); SCB;                    // retires aLo(31)
  __builtin_amdgcn_s_setprio(1); MM16(afLo, bfLo); __builtin_amdgcn_s_setprio(0); SCB;
  VMCNT(0); LGKM(0); SCB;                    // retires aHi(31)
  __builtin_amdgcn_s_setprio(1); MM16(afHi, bfHi); __builtin_amdgcn_s_setprio(0);

  // ---- epilogue: mu via LDS (stride-66 f32), lvp in regs, fused loss ------
  __syncthreads();
  float* ldsF = (float*)lds;
  float* mur = ldsF + (wid & 3) * 4224;      // 64x64 region, row stride 66
  if (wh == 0) {                             // mu waves publish mu + bias
#pragma unroll
    for (int ni = 0; ni < 4; ++ni) {
      const float bmv = b2m[bn0 + wn * 64 + ni * 16 + c16];
#pragma unroll
      for (int mi = 0; mi < 4; ++mi)
#pragma unroll
        for (int r = 0; r < 4; ++r)
          mur[(mi * 16 + quad * 4 + r) * 66 + ni * 16 + c16] =
              acc[mi][ni][r] + bmv;
    }
  }
  __syncthreads();
  const float invN = 1.0f / (float)NS;
  float s = 0.f;
  if (wh == 1) {                             // lv waves compute the loss
#pragma unroll
    for (int ni = 0; ni < 4; ++ni) {
      const int gcol = bn0 + wn * 64 + ni * 16 + c16;
      const float blv = b2l[gcol];
      const float syv = Sy[gcol], sy2v = Sy2[gcol];
#pragma unroll
      for (int mi = 0; mi < 4; ++mi)
#pragma unroll
        for (int r = 0; r < 4; ++r) {
          const int grow = bm0 + wm * 64 + mi * 16 + quad * 4 + r;
          const float m   = mur[(mi * 16 + quad * 4 + r) * 66 + ni * 16 + c16];
          const float lvp = acc[mi][ni][r] + blv;
          const float w   = 0.5f * expf(-tanhf(lvp));
          const float yv  = ld_in(y, yf, (size_t)grow * YD + gcol);
          s += w * (yv * yv - 2.f * m * yv + (2.f * m * syv - sy2v) * invN);
        }
    }
  }
  for (int off = 32; off > 0; off >>= 1) s += __shfl_down(s, off);
  if (lane == 0) bs[wid] = (double)s;
  __syncthreads();
  if (tid == 0) {
    atomicAdd(gacc, bs[0] + bs[1] + bs[2] + bs[3] +
                    bs[4] + bs[5] + bs[6] + bs[7]);
    __threadfence();
    const unsigned old = atomicAdd(counter, 1u);
    if (old == gridDim.x - 1) {
      const double g = atomicAdd(gacc, 0.0);
      out[0] = (float)(-g / (double)NS);
    }
  }
}

// ---------------- launch ----------------
extern "C" void kernel_launch(void* const* d_in, const int* in_sizes, int n_in,
                              void* d_out, int out_size, void* d_ws, size_t ws_size,
                              hipStream_t stream) {
  char* ws = (char*)d_ws;
  double*   gacc    = (double*)ws;               // [0,8)
  unsigned* counter = (unsigned*)(ws + 8);       // [8,12)
  float*    Sy      = (float*)(ws + 128);        // 512 f32
  float*    Sy2     = (float*)(ws + 2176);       // 512 f32
  float*    biasv   = (float*)(ws + 4224);       // 5120 f32 -> ends 24704
  u16* xb   = (u16*)(ws + 24704);                // [NS,XD] bf16, 8 MB
  u16* W1t  = xb + (size_t)NS * XD;              // [4096,512] 4 MB (both heads)
  u16* W2tm = W1t + (size_t)2 * HD * XD;         // [YD,HD] 2 MB
  u16* W2tl = W2tm + (size_t)YD * HD;            // 2 MB
  u16* h_mu = W2tl + (size_t)YD * HD;            // [NS,HD] bf16, 32 MB
  u16* h_lv = h_mu + (size_t)NS * HD;            // 32 MB  (~80 MB total)

  hipMemsetAsync(d_ws, 0, 4224, stream);         // gacc + counter + Sy + Sy2

  prep_all<<<2049 + 1024 + 64, 256, 0, stream>>>(
      d_in[0], d_in[2], d_in[3], d_in[4], d_in[5],
      d_in[6], d_in[7], d_in[8], d_in[9], d_in[1],
      xb, biasv, W1t, W2tm, W2tl, Sy, Sy2);

  const float* b1  = biasv;               // [4096] = b1m|b1l
  const float* b2m = biasv + 4096, *b2l = biasv + 4608;

  gemm1_kernel<<<(NS / 256) * ((2 * HD) / 256), 512, 0, stream>>>(
      d_in[0], xb, W1t, b1, h_mu, h_lv);

  gemm2_dual<<<(NS / 128) * (YD / 128), 512, 0, stream>>>(
      h_mu, h_lv, W2tm, W2tl, b2m, b2l, d_in[1], Sy, Sy2,
      gacc, counter, (float*)d_out);
}

// Round 10
// 236.549 us; speedup vs baseline: 1.1154x; 1.1154x over previous
//
#include <hip/hip_runtime.h>
#include <hip/hip_bf16.h>
#include <stdint.h>

// Problem constants (fixed by the reference)
#define NS   8192
#define XD   512
#define HD   2048
#define YD   512

typedef unsigned short u16;
using bf16x8 = __attribute__((ext_vector_type(8))) short;
using f32x4  = __attribute__((ext_vector_type(4))) float;

__device__ __forceinline__ float bf2f(u16 u) {
  union { uint32_t i; float f; } v; v.i = ((uint32_t)u) << 16; return v.f;
}
__device__ __forceinline__ u16 f2b(float f) {
  __hip_bfloat16 hb = __float2bfloat16(f);
  return *(const u16*)&hb;
}
// dtype-adaptive element load: f32 flag ? read float : read bf16
__device__ __forceinline__ float ld_in(const void* p, int f32, size_t i) {
  return f32 ? ((const float*)p)[i] : bf2f(((const u16*)p)[i]);
}
#define GLDS(gp, lp) __builtin_amdgcn_global_load_lds( \
    (__attribute__((address_space(1))) void*)(gp),     \
    (__attribute__((address_space(3))) void*)(lp), 16, 0, 0)

// ---------------- per-block dtype self-detection ----------------------------
__device__ __forceinline__ int probe_f32(const void* p, int n_u16, int* sflag) {
  if (threadIdx.x == 0) *sflag = 0;
  __syncthreads();
  const u16* q = (const u16*)p;
  int wild = 0;
  for (int i = threadIdx.x; i < n_u16; i += blockDim.x) {
    float v = bf2f(q[i]);
    if (!(fabsf(v) <= 1000.0f)) wild = 1;   // catches huge AND NaN
  }
  if (wild) *sflag = 1;
  __syncthreads();
  int r = *sflag;
  __syncthreads();                          // safe for back-to-back reuse
  return r;
}

// ---------------- fused prep: x->bf16, biases, 4 transposes, ystats ---------
// grid: [0,2048) x-convert | 2048 biases | [2049,3073) transposes |
//       [3073,3137) y column stats
__global__ __launch_bounds__(256) void prep_all(
    const void* __restrict__ x,
    const void* w1m, const void* b1m, const void* w2m, const void* b2m,
    const void* w1l, const void* b1l, const void* w2l, const void* b2l,
    const void* __restrict__ y,
    u16* __restrict__ xb, float* __restrict__ biasv,
    u16* __restrict__ W1t, u16* __restrict__ W2tm, u16* __restrict__ W2tl,
    float* __restrict__ Sy, float* __restrict__ Sy2) {
  __shared__ u16 tile[64 * 72];              // transpose staging (9216 B)
  __shared__ int sflag;
  const int b = blockIdx.x;
  const int tid = threadIdx.x;

  if (b < 2048) {                            // ---- x conversion (f32 only)
    if (!probe_f32(x, 1024, &sflag)) return; // bf16 -> gemm1 reads x directly
    const size_t base = (size_t)b * 2048 + (size_t)tid * 8;
    alignas(16) u16 o[8];
    const float4* s = (const float4*)((const float*)x + base);
    float4 v0 = s[0], v1 = s[1];
    o[0]=f2b(v0.x); o[1]=f2b(v0.y); o[2]=f2b(v0.z); o[3]=f2b(v0.w);
    o[4]=f2b(v1.x); o[5]=f2b(v1.y); o[6]=f2b(v1.z); o[7]=f2b(v1.w);
    *(uint4*)(xb + base) = *(const uint4*)o;
  } else if (b == 2048) {                    // ---- biases -> f32
    const int f3 = probe_f32(b1m, 1024, &sflag);
    const int f5 = probe_f32(b2m, 512, &sflag);
    const int f7 = probe_f32(b1l, 1024, &sflag);
    const int f9 = probe_f32(b2l, 512, &sflag);
    for (int i = tid; i < 5120; i += 256) {
      float v;
      if (i < 2048)      v = ld_in(b1m, f3, i);
      else if (i < 4096) v = ld_in(b1l, f7, i - 2048);
      else if (i < 4608) v = ld_in(b2m, f5, i - 4096);
      else               v = ld_in(b2l, f9, i - 4608);
      biasv[i] = v;
    }
  } else if (b < 3073) {                     // ---- 64x64-tile transposes
    const int id = b - 2049, which = id >> 8, t = id & 255;
    const void* in; u16* out; int R, C;
    if (which == 0)      { in = w1m; out = W1t;                   R = XD; C = HD; }
    else if (which == 1) { in = w2m; out = W2tm;                  R = HD; C = YD; }
    else if (which == 2) { in = w1l; out = W1t + (size_t)HD * XD; R = XD; C = HD; }
    else                 { in = w2l; out = W2tl;                  R = HD; C = YD; }
    const int f = probe_f32(in, 1024, &sflag);
    const int nbx = C >> 6;
    const int c0 = (t % nbx) * 64, r0 = (t / nbx) * 64;
    const int r = tid >> 2, cc = (tid & 3) * 16;
    if (f) {
      const float4* s = (const float4*)((const float*)in + (size_t)(r0 + r) * C + c0 + cc);
#pragma unroll
      for (int k = 0; k < 4; ++k) {
        float4 v = s[k];
        tile[r * 72 + cc + k * 4 + 0] = f2b(v.x);
        tile[r * 72 + cc + k * 4 + 1] = f2b(v.y);
        tile[r * 72 + cc + k * 4 + 2] = f2b(v.z);
        tile[r * 72 + cc + k * 4 + 3] = f2b(v.w);
      }
    } else {
      const uint4* s = (const uint4*)((const u16*)in + (size_t)(r0 + r) * C + c0 + cc);
      *(uint4*)&tile[r * 72 + cc]     = s[0];
      *(uint4*)&tile[r * 72 + cc + 8] = s[1];
    }
    __syncthreads();
    const int i = tid >> 2, jc = (tid & 3) * 16;
    alignas(16) u16 o[16];
#pragma unroll
    for (int j = 0; j < 16; ++j) o[j] = tile[(jc + j) * 72 + i];
    uint4* dq = (uint4*)&out[(size_t)(c0 + i) * R + r0 + jc];
    dq[0] = ((const uint4*)o)[0];
    dq[1] = ((const uint4*)o)[1];
  } else {                                   // ---- y column stats (64 blocks)
    const int id2 = b - 3073;
    const int yf = probe_f32(y, 1024, &sflag);
    const int half = tid >> 7;               // 0/1
    const int c0 = (tid & 127) * 4;
    const int r0 = id2 * 128 + half * 64;
    float s0 = 0.f, s1 = 0.f, s2 = 0.f, s3 = 0.f;
    float q0 = 0.f, q1 = 0.f, q2 = 0.f, q3 = 0.f;
    for (int r = r0; r < r0 + 64; r += 4) {
#pragma unroll
      for (int rr = 0; rr < 4; ++rr) {
        float v0, v1, v2, v3;
        if (yf) {
          const float4 t4 = *(const float4*)((const float*)y + (size_t)(r + rr) * YD + c0);
          v0 = t4.x; v1 = t4.y; v2 = t4.z; v3 = t4.w;
        } else {
          const uint2 t2 = *(const uint2*)((const u16*)y + (size_t)(r + rr) * YD + c0);
          v0 = bf2f((u16)(t2.x & 0xffff)); v1 = bf2f((u16)(t2.x >> 16));
          v2 = bf2f((u16)(t2.y & 0xffff)); v3 = bf2f((u16)(t2.y >> 16));
        }
        s0 += v0; q0 += v0 * v0;  s1 += v1; q1 += v1 * v1;
        s2 += v2; q2 += v2 * v2;  s3 += v3; q3 += v3 * v3;
      }
    }
    atomicAdd(&Sy[c0],     s0);  atomicAdd(&Sy2[c0],     q0);
    atomicAdd(&Sy[c0 + 1], s1);  atomicAdd(&Sy2[c0 + 1], q1);
    atomicAdd(&Sy[c0 + 2], s2);  atomicAdd(&Sy2[c0 + 2], q2);
    atomicAdd(&Sy[c0 + 3], s3);  atomicAdd(&Sy2[c0 + 3], q3);
  }
}

// ---------------- shared sync/pipeline macros -------------------------------
#define SYNC_PRE do { \
  __builtin_amdgcn_sched_barrier(0); \
  __builtin_amdgcn_s_barrier(); \
  asm volatile("s_waitcnt lgkmcnt(0)" ::: "memory"); \
  __builtin_amdgcn_sched_barrier(0); \
  __builtin_amdgcn_s_setprio(1); } while (0)
#define SYNC_POST do { \
  __builtin_amdgcn_s_setprio(0); \
  __builtin_amdgcn_sched_barrier(0); \
  __builtin_amdgcn_s_barrier(); \
  __builtin_amdgcn_sched_barrier(0); } while (0)
#define VMCNT(N) asm volatile("s_waitcnt vmcnt(" #N ")" ::: "memory")
#define SCB __builtin_amdgcn_sched_barrier(0)

// ---------------- GEMM1: 256x256 tile, 8-phase counted-vmcnt pipeline -------
// (verified round-0; unchanged)
#define RD_A(MH, BUF) do { \
  const u16* ab_ = &lds[((BUF)*2 + wm) * 8192]; \
  _Pragma("unroll") for (int q_ = 0; q_ < 4; ++q_) \
    _Pragma("unroll") for (int ks_ = 0; ks_ < 2; ++ks_) \
      af[q_][ks_] = *(const bf16x8*)&ab_[((MH)*64 + q_*16 + c16)*64 + (((ks_*4+quad) ^ cswz) << 3)]; \
} while (0)

#define RD_B(NH, BUF) do { \
  const u16* bb_ = &lds[32768 + ((BUF)*2 + (wn>>1)) * 8192]; \
  _Pragma("unroll") for (int p_ = 0; p_ < 2; ++p_) \
    _Pragma("unroll") for (int ks_ = 0; ks_ < 2; ++ks_) \
      bf[(NH)*2+p_][ks_] = *(const bf16x8*)&bb_[((wn&1)*64 + ((NH)*2+p_)*16 + c16)*64 + (((ks_*4+quad) ^ cswz) << 3)]; \
} while (0)

#define MM(MH, NH) do { \
  _Pragma("unroll") for (int ks_ = 0; ks_ < 2; ++ks_) \
    _Pragma("unroll") for (int q_ = 0; q_ < 4; ++q_) \
      _Pragma("unroll") for (int p_ = 0; p_ < 2; ++p_) \
        acc[(MH)*4+q_][(NH)*2+p_] = __builtin_amdgcn_mfma_f32_16x16x32_bf16( \
            af[q_][ks_], bf[(NH)*2+p_][ks_], acc[(MH)*4+q_][(NH)*2+p_], 0, 0, 0); \
} while (0)

#define ST_A(KT, HALF) do { if ((KT) < 8) { \
  u16* lb_ = &lds[(((KT)&1)*2 + (HALF))*8192 + (wid << 9)]; \
  const u16* sp_ = Aptr + (size_t)(bm0 + (HALF)*128 + (wid<<3) + srow)*512 + ((KT)<<6) + scg; \
  GLDS(sp_, lb_); GLDS(sp_ + (size_t)64*512, lb_ + 4096); } } while (0)

#define ST_B(KT, HALF) do { if ((KT) < 8) { \
  u16* lb_ = &lds[32768 + (((KT)&1)*2 + (HALF))*8192 + (wid << 9)]; \
  const u16* sp_ = W1t + (size_t)(bn0 + (HALF)*128 + (wid<<3) + srow)*512 + ((KT)<<6) + scg; \
  GLDS(sp_, lb_); GLDS(sp_ + (size_t)64*512, lb_ + 4096); } } while (0)

__global__ __launch_bounds__(512, 2) void gemm1_kernel(
    const void* __restrict__ xraw, const u16* __restrict__ xb,
    const u16* __restrict__ W1t,    // [4096, 512]
    const float* __restrict__ bias, // [4096]
    u16* __restrict__ h_mu, u16* __restrict__ h_lv) {
  __shared__ alignas(16) u16 lds[65536];     // 128 KB
  __shared__ int sflag;
  const int tid = threadIdx.x;

  const u16* Aptr = probe_f32(xraw, 1024, &sflag) ? xb : (const u16*)xraw;

  const int wid = tid >> 6, lane = tid & 63;
  const int wm = wid >> 2, wn = wid & 3;
  const int quad = lane >> 4, c16 = lane & 15, cswz = c16 & 7;
  const int srow = lane >> 3;
  const int scg  = ((lane & 7) ^ srow) << 3;

  const int id = blockIdx.x;
  const int xcd = id & 7, slot = id >> 3;    // 512 blocks, 64 slots/XCD
  const int bm0 = (xcd * 4 + (slot & 3)) * 256;
  const int bn0 = (slot >> 2) * 256;

  f32x4 acc[8][4] = {};
  bf16x8 af[4][2], bf[4][2];

  ST_B(0, 0); ST_B(0, 1); ST_A(0, 0); ST_A(0, 1);
  ST_B(1, 0); ST_B(1, 1);
  VMCNT(4);
  __builtin_amdgcn_s_barrier();
  __builtin_amdgcn_sched_barrier(0);

#pragma unroll
  for (int i = 0; i < 4; ++i) {
    const int ka = 2 * i, kb = ka + 1;
    const bool last = (i == 3);
    RD_A(0, 0); RD_B(0, 0); ST_A(kb, 0);
    SYNC_PRE; MM(0, 0); SYNC_POST;
    RD_B(1, 0); ST_A(kb, 1);
    SYNC_PRE; MM(0, 1); SYNC_POST;
    RD_A(1, 0); ST_B(ka + 2, 0);
    SYNC_PRE; MM(1, 0); SYNC_POST;
    ST_B(ka + 2, 1);
    SYNC_PRE; MM(1, 1);
    if (!last) { VMCNT(4); } else { VMCNT(0); }
    SYNC_POST;
    RD_A(0, 1); RD_B(0, 1); ST_A(ka + 2, 0);
    SYNC_PRE; MM(0, 0); SYNC_POST;
    RD_B(1, 1); ST_A(ka + 2, 1);
    SYNC_PRE; MM(0, 1); SYNC_POST;
    RD_A(1, 1); ST_B(kb + 2, 0);
    SYNC_PRE; MM(1, 0); SYNC_POST;
    ST_B(kb + 2, 1);
    SYNC_PRE; MM(1, 1);
    if (!last) { VMCNT(4); }
    SYNC_POST;
  }

  u16* myl = &lds[wid * 8192];
  const bool is_lv = bn0 >= HD;
  u16* dst = is_lv ? h_lv : h_mu;
  const int wncol = wn << 6;
  const int gc0 = (bn0 - (is_lv ? HD : 0)) + wncol;
  const int grow0 = bm0 + (wm << 7);
#pragma unroll
  for (int ni = 0; ni < 4; ++ni) {
    const float bv = bias[bn0 + wncol + ni * 16 + c16];
#pragma unroll
    for (int mi = 0; mi < 8; ++mi)
#pragma unroll
      for (int r = 0; r < 4; ++r) {
        const int row = mi * 16 + (quad << 2) + r;
        const int col = ni * 16 + c16;
        myl[row * 64 + ((((col >> 3) ^ (row & 7)) << 3) | (col & 7))] =
            f2b(fmaxf(acc[mi][ni][r] + bv, 0.f));
      }
  }
#pragma unroll
  for (int it = 0; it < 16; ++it) {
    const int row = (it << 3) + (lane >> 3);
    const int ch = lane & 7;
    const uint4 v = *(const uint4*)&myl[row * 64 + ((ch ^ (row & 7)) << 3)];
    *(uint4*)&dst[(size_t)(grow0 + row) * HD + gc0 + (ch << 3)] = v;
  }
}

#undef RD_A
#undef RD_B
#undef MM
#undef ST_A
#undef ST_B

// ---------------- GEMM2 v10: head-split waves, ALL-LDS (verified dataflow) --
// Rounds 3-9 post-mortem: every A-direct-from-global variant spilled (~20
// VGPRs of addr temps -> 10-20 MB scratch) regardless of ledger. Reverted to
// the round-2 verified LDS dataflow and applied the head-split THERE:
//   vs round-2: B LDS amplification 4x -> 2x (each wave touches only its
//   head's regions), LDS/K-tile 256 -> 192 KB, barriers/K-tile 4 -> 2.
// 8 waves: wh=wid>>2 (0=mu,1=lv), wm=(wid>>1)&1, wn=wid&1; per-wave 64x64 of
// its head's 128x128. Per K-tile per wave: 16 ds_read_b128 + 32 MFMA.
// LDS: 2 bufs x 64 KB; regions (u16): Am@0 Al@8192 Bm@16384 Bl@24576, each
// [128 rows][64 k] row-major with the verified source-XOR swizzle
// (LDS[r][c8] = src[r][c8^(r&7)]; reader XORs cswz = c16&7 = row&7).
// Schedule (1-ahead staging, round-2's 2-barrier skeleton):
//   phase t: RD 16 ds from buf[t&1] | ST4 tile t+1 -> buf[(t+1)&1] (8 GLDS,
//   bump-pointer addressing, zero temps) | SYNC_PRE (barrier+lgkm0+prio1) |
//   MM32 | VMCNT(0) (G(t+1) landed; ~1500 cyc cover vs L2-hot ~300) |
//   SYNC_POST.
// RAW: G(t) retired at phase t-1's VMCNT(0) before its POST barrier.
// WAR: ST4(t+1) overwrites tile t-1's buf; those reads retired at phase
// t-1's lgkm0 (before POST); writer issues after passing POST.
// Ledger: frags 64 + 8 stage ptrs 16 + misc ~15 = ~95 arch; acc -> AGPR
// (round-2 precedent: VGPR 96, zero scratch).
#define RDA8(BUF) do { \
  _Pragma("unroll") for (int mi_ = 0; mi_ < 4; ++mi_) \
    _Pragma("unroll") for (int ks_ = 0; ks_ < 2; ++ks_) \
      af[mi_][ks_] = *(const bf16x8*)&lds[(BUF)*32768 + abase + \
          (wm*64 + mi_*16 + c16)*64 + (((ks_*4+quad) ^ cswz) << 3)]; \
} while (0)

#define RDB8(BUF) do { \
  _Pragma("unroll") for (int ni_ = 0; ni_ < 4; ++ni_) \
    _Pragma("unroll") for (int ks_ = 0; ks_ < 2; ++ks_) \
      bf[ni_][ks_] = *(const bf16x8*)&lds[(BUF)*32768 + bbase + \
          (wn*64 + ni_*16 + c16)*64 + (((ks_*4+quad) ^ cswz) << 3)]; \
} while (0)

#define MM32 do { \
  _Pragma("unroll") for (int ks_ = 0; ks_ < 2; ++ks_) \
    _Pragma("unroll") for (int mi_ = 0; mi_ < 4; ++mi_) \
      _Pragma("unroll") for (int ni_ = 0; ni_ < 4; ++ni_) \
        acc[mi_][ni_] = __builtin_amdgcn_mfma_f32_16x16x32_bf16( \
            af[mi_][ks_], bf[ni_][ks_], acc[mi_][ni_], 0, 0, 0); \
} while (0)

// Stage one full K-tile (all 4 regions) into buffer BI from bump pointers.
#define ST4(BI) do { \
  u16* l_ = lds + (BI)*32768 + (wid << 9); \
  GLDS(pAm, l_);         GLDS(pAm2, l_ + 4096); \
  GLDS(pAl, l_ + 8192);  GLDS(pAl2, l_ + 12288); \
  GLDS(pBm, l_ + 16384); GLDS(pBm2, l_ + 20480); \
  GLDS(pBl, l_ + 24576); GLDS(pBl2, l_ + 28672); \
} while (0)

#define BUMP8 do { pAm += 64; pAm2 += 64; pAl += 64; pAl2 += 64; \
                   pBm += 64; pBm2 += 64; pBl += 64; pBl2 += 64; } while (0)

#define PH10(BR, BW) do { \
  SCB; RDA8(BR); RDB8(BR); SCB; \
  ST4(BW); SCB; BUMP8; SCB; \
  SYNC_PRE; \
  MM32; \
  VMCNT(0); \
  SYNC_POST; \
} while (0)

__global__ __launch_bounds__(512, 2) void gemm2_dual(
    const u16* __restrict__ hm, const u16* __restrict__ hl,
    const u16* __restrict__ W2m, const u16* __restrict__ W2l,  // [YD, HD]
    const float* __restrict__ b2m, const float* __restrict__ b2l,
    const void* __restrict__ y,
    const float* __restrict__ Sy, const float* __restrict__ Sy2,
    double* __restrict__ gacc, unsigned* __restrict__ counter,
    float* __restrict__ out) {
  __shared__ alignas(16) u16 lds[65536];     // 128 KB: 2 bufs x 64 KB
  __shared__ double bs[8];
  __shared__ int sflag;

  const int yf = probe_f32(y, 1024, &sflag);

  const int tid = threadIdx.x, wid = tid >> 6, lane = tid & 63;
  const int wh = wid >> 2;                   // 0 = mu, 1 = lv
  const int wm = (wid >> 1) & 1, wn = wid & 1;  // 2M x 2N within head
  const int quad = lane >> 4, c16 = lane & 15, cswz = c16 & 7;
  const int srow = lane >> 3;
  const int scg  = ((lane & 7) ^ srow) << 3;
  const int abase = wh ? 8192 : 0;           // Am@0 / Al@8192 (u16)
  const int bbase = 16384 + abase;           // Bm@16384 / Bl@24576

  // 256 blocks = 64 m-tiles x 4 n-tiles; N-fastest within XCD (W2 L2-hot).
  const int id = blockIdx.x;
  const int xcd = id & 7, slot = id >> 3;    // 32 slots/XCD
  const int bm0 = (xcd * 8 + (slot >> 2)) * 128;
  const int bn0 = (slot & 3) * 128;

  // Bump-pointer staging sources (all waves stage all 4 regions; +64 u16
  // per phase; zero per-load address arithmetic).
  const int strow = (wid << 3) + srow;       // staged row 0..63 (+64 for hi)
  const u16* pAm  = hm  + (size_t)(bm0 + strow) * HD + scg;
  const u16* pAm2 = pAm + (size_t)64 * HD;
  const u16* pAl  = hl  + (size_t)(bm0 + strow) * HD + scg;
  const u16* pAl2 = pAl + (size_t)64 * HD;
  const u16* pBm  = W2m + (size_t)(bn0 + strow) * HD + scg;
  const u16* pBm2 = pBm + (size_t)64 * HD;
  const u16* pBl  = W2l + (size_t)(bn0 + strow) * HD + scg;
  const u16* pBl2 = pBl + (size_t)64 * HD;

  f32x4 acc[4][4] = {};
  bf16x8 af[4][2], bf[4][2];

  // Prologue: stage tile 0 -> buf0; drain; barrier.
  ST4(0); BUMP8;
  VMCNT(0);
  __builtin_amdgcn_s_barrier();
  SCB;

  // Phases 0..29 (15 double iterations), then peeled 30 and 31.
#pragma unroll 1
  for (int i = 0; i < 15; ++i) {
    PH10(0, 1);
    PH10(1, 0);
  }
  PH10(0, 1);                                // phase 30: stages tile 31
  // Phase 31 (buf1): no stage; drain already complete (VMCNT(0) at ph30).
  SCB; RDA8(1); RDB8(1); SCB;
  SYNC_PRE;
  MM32;
  SYNC_POST;                                 // quiesce LDS before epilogue

  // ---- epilogue: mu via LDS (stride-66 f32), lvp in regs, fused loss ------
  // (verified in v9's passing run)
  float* ldsF = (float*)lds;
  float* mur = ldsF + (wid & 3) * 4224;      // 64x64 region, row stride 66
  if (wh == 0) {                             // mu waves publish mu + bias
#pragma unroll
    for (int ni = 0; ni < 4; ++ni) {
      const float bmv = b2m[bn0 + wn * 64 + ni * 16 + c16];
#pragma unroll
      for (int mi = 0; mi < 4; ++mi)
#pragma unroll
        for (int r = 0; r < 4; ++r)
          mur[(mi * 16 + quad * 4 + r) * 66 + ni * 16 + c16] =
              acc[mi][ni][r] + bmv;
    }
  }
  __syncthreads();
  const float invN = 1.0f / (float)NS;
  float s = 0.f;
  if (wh == 1) {                             // lv waves compute the loss
#pragma unroll
    for (int ni = 0; ni < 4; ++ni) {
      const int gcol = bn0 + wn * 64 + ni * 16 + c16;
      const float blv = b2l[gcol];
      const float syv = Sy[gcol], sy2v = Sy2[gcol];
#pragma unroll
      for (int mi = 0; mi < 4; ++mi)
#pragma unroll
        for (int r = 0; r < 4; ++r) {
          const int grow = bm0 + wm * 64 + mi * 16 + quad * 4 + r;
          const float m   = mur[(mi * 16 + quad * 4 + r) * 66 + ni * 16 + c16];
          const float lvp = acc[mi][ni][r] + blv;
          const float w   = 0.5f * expf(-tanhf(lvp));
          const float yv  = ld_in(y, yf, (size_t)grow * YD + gcol);
          s += w * (yv * yv - 2.f * m * yv + (2.f * m * syv - sy2v) * invN);
        }
    }
  }
  for (int off = 32; off > 0; off >>= 1) s += __shfl_down(s, off);
  if (lane == 0) bs[wid] = (double)s;
  __syncthreads();
  if (tid == 0) {
    atomicAdd(gacc, bs[0] + bs[1] + bs[2] + bs[3] +
                    bs[4] + bs[5] + bs[6] + bs[7]);
    __threadfence();
    const unsigned old = atomicAdd(counter, 1u);
    if (old == gridDim.x - 1) {
      const double g = atomicAdd(gacc, 0.0);
      out[0] = (float)(-g / (double)NS);
    }
  }
}

// ---------------- launch ----------------
extern "C" void kernel_launch(void* const* d_in, const int* in_sizes, int n_in,
                              void* d_out, int out_size, void* d_ws, size_t ws_size,
                              hipStream_t stream) {
  char* ws = (char*)d_ws;
  double*   gacc    = (double*)ws;               // [0,8)
  unsigned* counter = (unsigned*)(ws + 8);       // [8,12)
  float*    Sy      = (float*)(ws + 128);        // 512 f32
  float*    Sy2     = (float*)(ws + 2176);       // 512 f32
  float*    biasv   = (float*)(ws + 4224);       // 5120 f32 -> ends 24704
  u16* xb   = (u16*)(ws + 24704);                // [NS,XD] bf16, 8 MB
  u16* W1t  = xb + (size_t)NS * XD;              // [4096,512] 4 MB (both heads)
  u16* W2tm = W1t + (size_t)2 * HD * XD;         // [YD,HD] 2 MB
  u16* W2tl = W2tm + (size_t)YD * HD;            // 2 MB
  u16* h_mu = W2tl + (size_t)YD * HD;            // [NS,HD] bf16, 32 MB
  u16* h_lv = h_mu + (size_t)NS * HD;            // 32 MB  (~80 MB total)

  hipMemsetAsync(d_ws, 0, 4224, stream);         // gacc + counter + Sy + Sy2

  prep_all<<<2049 + 1024 + 64, 256, 0, stream>>>(
      d_in[0], d_in[2], d_in[3], d_in[4], d_in[5],
      d_in[6], d_in[7], d_in[8], d_in[9], d_in[1],
      xb, biasv, W1t, W2tm, W2tl, Sy, Sy2);

  const float* b1  = biasv;               // [4096] = b1m|b1l
  const float* b2m = biasv + 4096, *b2l = biasv + 4608;

  gemm1_kernel<<<(NS / 256) * ((2 * HD) / 256), 512, 0, stream>>>(
      d_in[0], xb, W1t, b1, h_mu, h_lv);

  gemm2_dual<<<(NS / 128) * (YD / 128), 512, 0, stream>>>(
      h_mu, h_lv, W2tm, W2tl, b2m, b2l, d_in[1], Sy, Sy2,
      gacc, counter, (float*)d_out);
}